// Round 6
// baseline (1090.587 us; speedup 1.0000x reference)
//
#include <hip/hip_runtime.h>
#include <stdint.h>

// Problem constants
#define BTOT 131072
#define S2   (131072 * 20)   // per-head plane: B*20 = 2,621,440 elements

__device__ __forceinline__ uint32_t rotl32(uint32_t x, int d) {
  return (x << d) | (x >> (32 - d));   // compiler emits v_alignbit_b32
}

#define TFR(r) { x0 += x1; x1 = rotl32(x1, (r)); x1 ^= x0; }

// JAX partitionable threefry, 32-bit draw:
//   counts_hi = 0, counts_lo = i;  bits1, bits2 = threefry2x32(key=(0,42),
//   x0 = counts_hi + ks[0] = 0, x1 = counts_lo + ks[1] = i + 42)
//   draw = bits1 ^ bits2        (jax/_src/prng.py, bit_width in [8,16,32])
__device__ __forceinline__ uint32_t tf_xor(uint32_t i) {
  const uint32_t k1 = 42u, k2 = 0x1BD11BF0u;  // 0x1BD11BDA ^ 0 ^ 42
  uint32_t x0 = 0u;            // counts_hi(=0) + ks[0](=0)
  uint32_t x1 = i + k1;        // counts_lo + ks[1](=42)
  TFR(13); TFR(15); TFR(26); TFR(6);   x0 += k1;  x1 += k2 + 1u;
  TFR(17); TFR(29); TFR(16); TFR(24);  x0 += k2;  x1 += 2u;        // +ks0+2
  TFR(13); TFR(15); TFR(26); TFR(6);   /*x0+=0*/  x1 += k1 + 3u;
  TFR(17); TFR(29); TFR(16); TFR(24);  x0 += k1;  x1 += k2 + 4u;
  TFR(13); TFR(15); TFR(26); TFR(6);   x0 += k2;  x1 += 5u;        // +ks0+5
  return x0 ^ x1;
}

// One thread per row b.  256 threads/block -> 512 blocks.
__global__ __launch_bounds__(256, 2) void fused_net(
    const float* __restrict__ x,  const float* __restrict__ W1,
    const float* __restrict__ b1, const float* __restrict__ Wh,
    const float* __restrict__ bh, float* __restrict__ out) {
  // per-wave transpose buffer: 4 waves x (64 rows * 20 cols)
  __shared__ float lds[4][64 * 20];

  const int tid  = threadIdx.x;
  const int wv   = tid >> 6;
  const int lane = tid & 63;
  const int b    = blockIdx.x * 256 + tid;        // this thread's row
  const int wb0  = blockIdx.x * 256 + wv * 64;    // wave's first row

  // ---- phase A: trunk h = relu(x @ W1^T + b1) ----
  float xr[20];
  const float4* xv = (const float4*)(x + (size_t)b * 20);
  #pragma unroll
  for (int i = 0; i < 5; ++i) {
    float4 v = xv[i];
    xr[4*i+0] = v.x; xr[4*i+1] = v.y; xr[4*i+2] = v.z; xr[4*i+3] = v.w;
  }
  float h[60];
  #pragma unroll 4
  for (int j = 0; j < 60; ++j) {
    float acc = b1[j];
    #pragma unroll
    for (int d = 0; d < 20; ++d) acc += xr[d] * W1[j * 20 + d];
    h[j] = fmaxf(acc, 0.f);
  }

  // ---- phase B: 40 heads, per-element threefry(xor) dropout ----
  #pragma unroll 1
  for (int k = 0; k < 40; ++k) {
    #pragma unroll 1
    for (int i = 0; i < 5; ++i) {          // o in quads: o = 4*i + q
      float4 v;
      float* p = (float*)&v;
      #pragma unroll
      for (int q = 0; q < 4; ++q) {
        const int o = i * 4 + q;
        float s = bh[k * 20 + o];
        const float* w = Wh + (size_t)(k * 20 + o) * 60;
        #pragma unroll
        for (int hh = 0; hh < 60; ++hh) s += h[hh] * w[hh];
        const uint32_t idx = (uint32_t)k * (uint32_t)S2
                           + (uint32_t)b * 20u + (uint32_t)o;
        p[q] = (tf_xor(idx) >> 31) ? 0.f : 2.f * fmaxf(s, 0.f);
      }
      ((float4*)lds[wv])[lane * 5 + i] = v;
    }
    // ensure all lanes' LDS writes land before cross-lane reads
    asm volatile("s_waitcnt lgkmcnt(0)" ::: "memory");
    // wave-local transpose -> perfectly coalesced float4 stores
    #pragma unroll
    for (int pp = 0; pp < 5; ++pp) {
      float4 v = ((float4*)lds[wv])[pp * 64 + lane];
      *(float4*)(out + (size_t)k * S2 + (size_t)wb0 * 20 + pp * 256 + lane * 4) = v;
    }
    asm volatile("s_waitcnt lgkmcnt(0)" ::: "memory");
  }
}

extern "C" void kernel_launch(void* const* d_in, const int* in_sizes, int n_in,
                              void* d_out, int out_size, void* d_ws, size_t ws_size,
                              hipStream_t stream) {
  const float* x  = (const float*)d_in[0];
  const float* W1 = (const float*)d_in[1];
  const float* b1 = (const float*)d_in[2];
  const float* Wh = (const float*)d_in[3];
  const float* bh = (const float*)d_in[4];
  float* out = (float*)d_out;
  fused_net<<<dim3(BTOT / 256), dim3(256), 0, stream>>>(x, W1, b1, Wh, bh, out);
}

// Round 7
// 783.443 us; speedup vs baseline: 1.3920x; 1.3920x over previous
//
#include <hip/hip_runtime.h>
#include <stdint.h>

// Problem constants
#define BTOT 131072
#define S2   (131072 * 20)   // per-head plane: B*20 = 2,621,440 elements
#define KSPLIT 4             // head-groups per row-block (10 heads each)

__device__ __forceinline__ uint32_t rotl32(uint32_t x, int d) {
  return (x << d) | (x >> (32 - d));   // compiler emits v_alignbit_b32
}

#define TFR(r) { x0 += x1; x1 = rotl32(x1, (r)); x1 ^= x0; }

// JAX partitionable threefry, 32-bit draw = bits_hi ^ bits_lo (verified r6):
//   threefry2x32(key=(0,42), x0 = counts_hi(=0)+0, x1 = counts_lo(=i)+42)
__device__ __forceinline__ uint32_t tf_xor(uint32_t i) {
  const uint32_t k1 = 42u, k2 = 0x1BD11BF0u;  // 0x1BD11BDA ^ 0 ^ 42
  uint32_t x0 = 0u;
  uint32_t x1 = i + k1;
  TFR(13); TFR(15); TFR(26); TFR(6);   x0 += k1;  x1 += k2 + 1u;
  TFR(17); TFR(29); TFR(16); TFR(24);  x0 += k2;  x1 += 2u;
  TFR(13); TFR(15); TFR(26); TFR(6);   /*x0+=0*/  x1 += k1 + 3u;
  TFR(17); TFR(29); TFR(16); TFR(24);  x0 += k1;  x1 += k2 + 4u;
  TFR(13); TFR(15); TFR(26); TFR(6);   x0 += k2;  x1 += 5u;
  return x0 ^ x1;
}

// 2048 blocks: blockIdx = (row-group, head-group).  8 blocks/CU (LDS-limited).
__global__ __launch_bounds__(256, 8) void fused_net(
    const float* __restrict__ x,  const float* __restrict__ W1,
    const float* __restrict__ b1, const float* __restrict__ Wh,
    const float* __restrict__ bh, float* __restrict__ out) {
  // per-wave transpose buffer: 4 waves x (64 rows * 20 cols)
  __shared__ float lds[4][64 * 20];

  const int tid  = threadIdx.x;
  const int wv   = tid >> 6;
  const int lane = tid & 63;
  const int kg   = blockIdx.x & (KSPLIT - 1);     // head group: 10 heads
  const int bg   = blockIdx.x >> 2;               // row group: 256 rows
  const int b    = bg * 256 + tid;                // this thread's row
  const int wb0  = bg * 256 + wv * 64;            // wave's first row
  const int k0   = kg * (40 / KSPLIT);

  // ---- phase A: trunk h = relu(x @ W1^T + b1) ----
  float xr[20];
  const float4* xv = (const float4*)(x + (size_t)b * 20);
  #pragma unroll
  for (int i = 0; i < 5; ++i) {
    float4 v = xv[i];
    xr[4*i+0] = v.x; xr[4*i+1] = v.y; xr[4*i+2] = v.z; xr[4*i+3] = v.w;
  }
  float h[60];
  #pragma unroll 4
  for (int j = 0; j < 60; ++j) {
    float acc = b1[j];
    #pragma unroll
    for (int d = 0; d < 20; ++d) acc += xr[d] * W1[j * 20 + d];
    h[j] = fmaxf(acc, 0.f);
  }

  // ---- phase B: 10 heads, per-element threefry(xor) dropout ----
  #pragma unroll 1
  for (int k = k0; k < k0 + (40 / KSPLIT); ++k) {
    #pragma unroll 1
    for (int i = 0; i < 5; ++i) {          // o in quads: o = 4*i + q
      float4 v;
      float* p = (float*)&v;
      #pragma unroll
      for (int q = 0; q < 4; ++q) {
        const int o = i * 4 + q;
        float s = bh[k * 20 + o];
        const float* w = Wh + (size_t)(k * 20 + o) * 60;
        #pragma unroll
        for (int hh = 0; hh < 60; ++hh) s += h[hh] * w[hh];
        const uint32_t idx = (uint32_t)k * (uint32_t)S2
                           + (uint32_t)b * 20u + (uint32_t)o;
        p[q] = (tf_xor(idx) >> 31) ? 0.f : 2.f * fmaxf(s, 0.f);
      }
      ((float4*)lds[wv])[lane * 5 + i] = v;
    }
    // ensure all lanes' LDS writes land before cross-lane reads
    asm volatile("s_waitcnt lgkmcnt(0)" ::: "memory");
    // wave-local transpose -> perfectly coalesced float4 stores
    #pragma unroll
    for (int pp = 0; pp < 5; ++pp) {
      float4 v = ((float4*)lds[wv])[pp * 64 + lane];
      *(float4*)(out + (size_t)k * S2 + (size_t)wb0 * 20 + pp * 256 + lane * 4) = v;
    }
    asm volatile("s_waitcnt lgkmcnt(0)" ::: "memory");
  }
}

extern "C" void kernel_launch(void* const* d_in, const int* in_sizes, int n_in,
                              void* d_out, int out_size, void* d_ws, size_t ws_size,
                              hipStream_t stream) {
  const float* x  = (const float*)d_in[0];
  const float* W1 = (const float*)d_in[1];
  const float* b1 = (const float*)d_in[2];
  const float* Wh = (const float*)d_in[3];
  const float* bh = (const float*)d_in[4];
  float* out = (float*)d_out;
  fused_net<<<dim3((BTOT / 256) * KSPLIT), dim3(256), 0, stream>>>(x, W1, b1, Wh, bh, out);
}